// Round 26
// baseline (43.696 us; speedup 1.0000x reference)
//
#include <hip/hip_runtime.h>
#include <hip/hip_bf16.h>
#include <utility>

#define LOG2E 1.4426950408889634f

#if __has_builtin(__builtin_amdgcn_exp2f)
#define EXP2F(x) __builtin_amdgcn_exp2f(x)
#else
#define EXP2F(x) exp2f(x)
#endif

#if __has_builtin(__builtin_amdgcn_rsqf)
#define RSQ(x) __builtin_amdgcn_rsqf(x)
#else
#define RSQ(x) (1.0f / sqrtf(x))
#endif

// readlane: lane may be a literal OR a runtime-uniform (SGPR) value.
#define RDLANE(x, l) __int_as_float(__builtin_amdgcn_readlane(__float_as_int(x), (l)))

// ---------------------------------------------------------------------------
// Kernel 1, R24 (3rd submit, untested due to infra): BLOCKED panel-4
// Cholesky. Per 4-column group: panel factorized in 4 fixed registers
// (10 readlanes, no LDS), ONE publish (float4/lane) + ONE wait, then a
// single burst of 60 uniform b128 reads feeding 240 independent fmas
// (rank-4 update, fully pipelined). Wait boundaries: 64 -> 16.
// ---------------------------------------------------------------------------
typedef float f16v __attribute__((ext_vector_type(16)));
struct Rows { f16v v0, v1, v2, v3; };

template<int J> __device__ __forceinline__ float getR(const Rows& r) {
    if constexpr (J < 16)      return r.v0[J];
    else if constexpr (J < 32) return r.v1[J - 16];
    else if constexpr (J < 48) return r.v2[J - 32];
    else                       return r.v3[J - 48];
}
template<int J> __device__ __forceinline__ void setR(Rows& r, float x) {
    if constexpr (J < 16)      r.v0[J] = x;
    else if constexpr (J < 32) r.v1[J - 16] = x;
    else if constexpr (J < 48) r.v2[J - 32] = x;
    else                       r.v3[J - 48] = x;
}

template<int LO, int W>
__device__ __forceinline__ float selR(const Rows& r, int k) {
    if constexpr (W == 1) {
        return getR<LO>(r);
    } else {
        float lo = selR<LO, W / 2>(r, k);
        float hi = selR<LO + W / 2, W / 2>(r, k);
        return (k & (W / 2)) ? hi : lo;   // uniform cond -> cndmask, CSE'd
    }
}

template<int... Js>
__device__ __forceinline__ void load_row(Rows& r, const float* Lrow,
                                         std::integer_sequence<int, Js...>) {
    (setR<Js>(r, Lrow[Js]), ...);
}

// Rank-4 update of one 4-column quad: r[4Q+jj] -= sum_kk lk_kk * L[4Q+jj][kk],
// where L[j][0..3] = lkbuf4[j] (uniform broadcast b128 reads).
template<int Q>
__device__ __forceinline__ void upd4(Rows& r, float lk0, float lk1, float lk2,
                                     float lk3, const float4* lkb) {
    float4 L0 = lkb[4 * Q + 0];
    float4 L1 = lkb[4 * Q + 1];
    float4 L2 = lkb[4 * Q + 2];
    float4 L3 = lkb[4 * Q + 3];
    setR<4*Q+0>(r, fmaf(-lk3, L0.w, fmaf(-lk2, L0.z, fmaf(-lk1, L0.y, fmaf(-lk0, L0.x, getR<4*Q+0>(r))))));
    setR<4*Q+1>(r, fmaf(-lk3, L1.w, fmaf(-lk2, L1.z, fmaf(-lk1, L1.y, fmaf(-lk0, L1.x, getR<4*Q+1>(r))))));
    setR<4*Q+2>(r, fmaf(-lk3, L2.w, fmaf(-lk2, L2.z, fmaf(-lk1, L2.y, fmaf(-lk0, L2.x, getR<4*Q+2>(r))))));
    setR<4*Q+3>(r, fmaf(-lk3, L3.w, fmaf(-lk2, L3.z, fmaf(-lk1, L3.y, fmaf(-lk0, L3.x, getR<4*Q+3>(r))))));
}
template<int QLO, int... Qs>
__device__ __forceinline__ void upd4_all(Rows& r, float lk0, float lk1,
                                         float lk2, float lk3, const float4* lkb,
                                         std::integer_sequence<int, Qs...>) {
    (upd4<QLO + Qs>(r, lk0, lk1, lk2, lk3, lkb), ...);
}

template<int GLO, int GHI, int ULO>
__device__ __forceinline__ void chol_groups(Rows& r, float* Lsh,
                                            float4* lkbuf4, int lane) {
#pragma clang loop unroll(disable)
    for (int g = GLO; g < GHI; ++g) {
        const int k0 = 4 * g;
        // Panel copy via sel-trees (uniform k -> cndmask, CSE'd).
        float t0 = selR<ULO, 64 - ULO>(r, k0 + 0);
        float t1 = selR<ULO, 64 - ULO>(r, k0 + 1);
        float t2 = selR<ULO, 64 - ULO>(r, k0 + 2);
        float t3 = selR<ULO, 64 - ULO>(r, k0 + 3);
        // 4x4 panel factorization, registers only.
        float i0  = RSQ(RDLANE(t0, k0 + 0));
        float lk0 = t0 * i0;
        t1 = fmaf(-lk0, RDLANE(lk0, k0 + 1), t1);
        t2 = fmaf(-lk0, RDLANE(lk0, k0 + 2), t2);
        t3 = fmaf(-lk0, RDLANE(lk0, k0 + 3), t3);
        float i1  = RSQ(RDLANE(t1, k0 + 1));
        float lk1 = t1 * i1;
        t2 = fmaf(-lk1, RDLANE(lk1, k0 + 2), t2);
        t3 = fmaf(-lk1, RDLANE(lk1, k0 + 3), t3);
        float i2  = RSQ(RDLANE(t2, k0 + 2));
        float lk2 = t2 * i2;
        t3 = fmaf(-lk2, RDLANE(lk2, k0 + 3), t3);
        float i3  = RSQ(RDLANE(t3, k0 + 3));
        float lk3 = t3 * i3;
        // Sink the 4 columns (diag slots hold reciprocals). b32 stride-65:
        // conflict-free.
        Lsh[lane * 65 + k0 + 0] = (lane == k0 + 0) ? i0 : lk0;
        Lsh[lane * 65 + k0 + 1] = (lane == k0 + 1) ? i1 : lk1;
        Lsh[lane * 65 + k0 + 2] = (lane == k0 + 2) ? i2 : lk2;
        Lsh[lane * 65 + k0 + 3] = (lane == k0 + 3) ? i3 : lk3;
        // Publish all 4 lk vectors; single wait; pipelined rank-4 burst.
        lkbuf4[lane] = make_float4(lk0, lk1, lk2, lk3);
        upd4_all<ULO / 4>(r, lk0, lk1, lk2, lk3, lkbuf4,
                          std::make_integer_sequence<int, 16 - ULO / 4>{});
    }
}

__global__ __launch_bounds__(64, 1)
void gp_precompute(const float* __restrict__ Z, const float* __restrict__ U,
                   const float* __restrict__ sf_p, const float* __restrict__ ell_p,
                   float* __restrict__ ws) {
    __shared__ float Lsh[64 * 65];
    __shared__ float4 zbuf[64];
    __shared__ float4 lkbuf4[64];
    const int lane = threadIdx.x;          // 64 threads = 1 wave
    const float sf  = sf_p[0];
    const float ell = ell_p[0];
    const float inv_ell = 1.0f / ell;
    const float sf2 = sf * sf;

    const float z0 = Z[lane * 3 + 0] * inv_ell;
    const float z1 = Z[lane * 3 + 1] * inv_ell;
    const float z2 = Z[lane * 3 + 2] * inv_ell;

    zbuf[lane] = make_float4(z0, z1, z2, 0.0f);
    __syncthreads();

    // Kzz row init: one uniform b128 per j.
#pragma unroll 4
    for (int j = 0; j < 64; ++j) {
        float4 zj = zbuf[j];
        float dx = z0 - zj.x;
        float dy = z1 - zj.y;
        float dz = z2 - zj.z;
        float sq = dx * dx + dy * dy + dz * dz;
        Lsh[lane * 65 + j] = sf2 * EXP2F(-0.5f * LOG2E * sq);
    }
    __syncthreads();

    Rows r;
    load_row(r, &Lsh[lane * 65], std::make_integer_sequence<int, 64>{});

    chol_groups< 0,  8,  0>(r, Lsh, lkbuf4, lane);
    chol_groups< 8, 12, 32>(r, Lsh, lkbuf4, lane);
    chol_groups<12, 16, 48>(r, Lsh, lkbuf4, lane);
    __syncthreads();

    // Solve L^T W = U (column sweep, descending i).
    float s0 = U[lane * 2 + 0];
    float s1 = U[lane * 2 + 1];
    float w0v = 0.0f, w1v = 0.0f;
#pragma unroll 8
    for (int i = 63; i >= 0; --i) {
        float a   = Lsh[i * 65 + lane];    // L[i][lane]; lane i: 1/L[i][i]
        float rdi = RDLANE(a, i);          // 1/L[i][i]
        float w0  = RDLANE(s0, i) * rdi;   // W[i][0]
        float w1  = RDLANE(s1, i) * rdi;   // W[i][1]
        bool  me  = (lane == i);
        w0v = me ? w0 : w0v;
        w1v = me ? w1 : w1v;
        s0 = fmaf(-a, w0, s0);             // lanes >= i polluted after use
        s1 = fmaf(-a, w1, s1);
    }

    const float dm = -0.5f * LOG2E * (z0 * z0 + z1 * z1 + z2 * z2);
    float4* ws4 = (float4*)ws;
    ws4[lane * 2 + 0] = make_float4(z0, z1, z2, dm);
    ws4[lane * 2 + 1] = make_float4(sf2 * w0v, sf2 * w1v, 0.0f, 0.0f);
}

// ---------------------------------------------------------------------------
// Kernel 2 (byte-identical to R23): R14 body, grid-strided ~2 chunks/block.
// ---------------------------------------------------------------------------
__global__ __launch_bounds__(256) void gp_forward(const float* __restrict__ X,
                                                  const float* __restrict__ ws,
                                                  const float* __restrict__ ell_p,
                                                  float* __restrict__ out,
                                                  int n, int nChunks) {
    __shared__ float4 P[128];   // 64 structs of {zs0,zs1,zs2,dm | w0,w1,0,0}
    for (int i = threadIdx.x; i < 128; i += 256)
        P[i] = ((const float4*)ws)[i];
    const float inv_ell = 1.0f / ell_p[0];
    __syncthreads();

    for (int chunk = blockIdx.x; chunk < nChunks; chunk += gridDim.x) {
        const int t  = chunk * 256 + (int)threadIdx.x;
        const int i0 = 2 * t;

        float p00, p01, p02, p10, p11, p12;
        if (i0 + 1 < n) {
            const float2* X2 = (const float2*)X;
            float2 xa = X2[3 * t + 0];
            float2 xb = X2[3 * t + 1];
            float2 xc = X2[3 * t + 2];
            p00 = xa.x; p01 = xa.y; p02 = xb.x;
            p10 = xb.y; p11 = xc.x; p12 = xc.y;
        } else if (i0 < n) {
            p00 = X[3 * i0 + 0]; p01 = X[3 * i0 + 1]; p02 = X[3 * i0 + 2];
            p10 = p00; p11 = p01; p12 = p02;
        } else {
            p00 = p01 = p02 = p10 = p11 = p12 = 0.0f;
        }

        float xt0[2], xt1[2], xt2[2], c[2];
        {
            float xs0 = p00 * inv_ell, xs1 = p01 * inv_ell, xs2 = p02 * inv_ell;
            c[0]  = -0.5f * LOG2E * (xs0 * xs0 + xs1 * xs1 + xs2 * xs2);
            xt0[0] = xs0 * LOG2E; xt1[0] = xs1 * LOG2E; xt2[0] = xs2 * LOG2E;
            xs0 = p10 * inv_ell; xs1 = p11 * inv_ell; xs2 = p12 * inv_ell;
            c[1]  = -0.5f * LOG2E * (xs0 * xs0 + xs1 * xs1 + xs2 * xs2);
            xt0[1] = xs0 * LOG2E; xt1[1] = xs1 * LOG2E; xt2[1] = xs2 * LOG2E;
        }

        float acc0[2] = {0.f, 0.f};
        float acc1[2] = {0.f, 0.f};

#pragma unroll 4
        for (int m = 0; m < 64; ++m) {
            const float4 a = P[2 * m + 0];
            const float4 b = P[2 * m + 1];
#pragma unroll
            for (int p = 0; p < 2; ++p) {
                float arg = fmaf(xt0[p], a.x,
                            fmaf(xt1[p], a.y,
                            fmaf(xt2[p], a.z, c[p] + a.w)));
                float e = EXP2F(arg);
                acc0[p] = fmaf(e, b.x, acc0[p]);
                acc1[p] = fmaf(e, b.y, acc1[p]);
            }
        }

        if (i0 + 1 < n) {
            ((float4*)out)[t] = make_float4(acc0[0], acc1[0], acc0[1], acc1[1]);
        } else if (i0 < n) {
            ((float2*)out)[i0] = make_float2(acc0[0], acc1[0]);
        }
    }
}

extern "C" void kernel_launch(void* const* d_in, const int* in_sizes, int n_in,
                              void* d_out, int out_size, void* d_ws, size_t ws_size,
                              hipStream_t stream) {
    // setup_inputs order: t, X, Z, U, sf, ell
    const float* X    = (const float*)d_in[1];
    const float* Z    = (const float*)d_in[2];
    const float* U    = (const float*)d_in[3];
    const float* sf   = (const float*)d_in[4];
    const float* ell  = (const float*)d_in[5];
    float* out = (float*)d_out;
    float* ws  = (float*)d_ws;
    const int N = in_sizes[1] / 3;

    gp_precompute<<<1, 64, 0, stream>>>(Z, U, sf, ell, ws);

    const int nChunks = (N + 511) / 512;    // 512 points (2/thread) per chunk
    int blocks = (nChunks + 1) / 2;         // ~2 chunks per block: 489 blocks
    if (blocks < 1) blocks = 1;
    gp_forward<<<blocks, 256, 0, stream>>>(X, ws, ell, out, N, nChunks);
}

// Round 27
// 38.602 us; speedup vs baseline: 1.1320x; 1.1320x over previous
//
#include <hip/hip_runtime.h>
#include <hip/hip_bf16.h>
#include <utility>

#define LOG2E 1.4426950408889634f

#if __has_builtin(__builtin_amdgcn_exp2f)
#define EXP2F(x) __builtin_amdgcn_exp2f(x)
#else
#define EXP2F(x) exp2f(x)
#endif

#if __has_builtin(__builtin_amdgcn_rsqf)
#define RSQ(x) __builtin_amdgcn_rsqf(x)
#else
#define RSQ(x) (1.0f / sqrtf(x))
#endif

// readlane: lane may be a literal OR a runtime-uniform (SGPR) value.
#define RDLANE(x, l) __int_as_float(__builtin_amdgcn_readlane(__float_as_int(x), (l)))

// ---------------------------------------------------------------------------
// R27 = R23 restore (best measured: 38.5 us). R24's panel-4 regressed to
// 43.7 (4x sel-tree work + panel readlane hazards > saved wait boundaries).
// Kernel 1: R21 barrier-free LDS-quad-broadcast Cholesky, one wave.
// ---------------------------------------------------------------------------
typedef float f16v __attribute__((ext_vector_type(16)));
struct Rows { f16v v0, v1, v2, v3; };

template<int J> __device__ __forceinline__ float getR(const Rows& r) {
    if constexpr (J < 16)      return r.v0[J];
    else if constexpr (J < 32) return r.v1[J - 16];
    else if constexpr (J < 48) return r.v2[J - 32];
    else                       return r.v3[J - 48];
}
template<int J> __device__ __forceinline__ void setR(Rows& r, float x) {
    if constexpr (J < 16)      r.v0[J] = x;
    else if constexpr (J < 32) r.v1[J - 16] = x;
    else if constexpr (J < 48) r.v2[J - 32] = x;
    else                       r.v3[J - 48] = x;
}

template<int LO, int W>
__device__ __forceinline__ float selR(const Rows& r, int k) {
    if constexpr (W == 1) {
        return getR<LO>(r);
    } else {
        float lo = selR<LO, W / 2>(r, k);
        float hi = selR<LO + W / 2, W / 2>(r, k);
        return (k & (W / 2)) ? hi : lo;   // uniform cond -> cndmask, CSE'd
    }
}

// Rank-1 update of one 4-column quad from a uniform float4 of lk values.
template<int Q>
__device__ __forceinline__ void upd_quad(Rows& r, float lk, const float4 lv) {
    setR<4 * Q + 0>(r, fmaf(-lk, lv.x, getR<4 * Q + 0>(r)));
    setR<4 * Q + 1>(r, fmaf(-lk, lv.y, getR<4 * Q + 1>(r)));
    setR<4 * Q + 2>(r, fmaf(-lk, lv.z, getR<4 * Q + 2>(r)));
    setR<4 * Q + 3>(r, fmaf(-lk, lv.w, getR<4 * Q + 3>(r)));
}
template<int QLO, int... Qs>
__device__ __forceinline__ void upd_quads(Rows& r, float lk, const float4* lkb4,
                                          std::integer_sequence<int, Qs...>) {
    (upd_quad<QLO + Qs>(r, lk, lkb4[QLO + Qs]), ...);
}

template<int... Js>
__device__ __forceinline__ void load_row(Rows& r, const float* Lrow,
                                         std::integer_sequence<int, Js...>) {
    (setR<Js>(r, Lrow[Js]), ...);
}

template<int KLO, int KHI, int ULO>
__device__ __forceinline__ void chol_phase(Rows& r, float* Lsh, float* lkbuf,
                                           int lane) {
    const float4* lkb4 = (const float4*)lkbuf;
#pragma clang loop unroll(disable)
    for (int k = KLO; k < KHI; ++k) {
        float rk  = selR<ULO, 64 - ULO>(r, k); // A[l][k] (valid l >= k)
        float dk  = RDLANE(rk, k);             // A[k][k], uniform
        float inv = RSQ(dk);                   // 1/L[k][k]
        float lk  = rk * inv;                  // L[l][k]
        float st  = (lane == k) ? inv : lk;    // diag slot stores reciprocal
        Lsh[lane * 65 + k] = st;               // sink column k (conflict-free)
        lkbuf[lane] = lk;                      // publish lk for the update
        // No s_barrier: single-wave DS is in-order; compiler inserts lgkmcnt.
        upd_quads<ULO / 4>(r, lk, lkb4,
                           std::make_integer_sequence<int, 16 - ULO / 4>{});
    }
}

__global__ __launch_bounds__(64, 1)
void gp_precompute(const float* __restrict__ Z, const float* __restrict__ U,
                   const float* __restrict__ sf_p, const float* __restrict__ ell_p,
                   float* __restrict__ ws) {
    __shared__ float Lsh[64 * 65];
    __shared__ float4 zbuf[64];
    __shared__ __align__(16) float lkbuf[64];
    const int lane = threadIdx.x;          // 64 threads = 1 wave
    const float sf  = sf_p[0];
    const float ell = ell_p[0];
    const float inv_ell = 1.0f / ell;
    const float sf2 = sf * sf;

    const float z0 = Z[lane * 3 + 0] * inv_ell;
    const float z1 = Z[lane * 3 + 1] * inv_ell;
    const float z2 = Z[lane * 3 + 2] * inv_ell;

    zbuf[lane] = make_float4(z0, z1, z2, 0.0f);
    __syncthreads();

    // Kzz row init: one uniform b128 per j.
#pragma unroll 4
    for (int j = 0; j < 64; ++j) {
        float4 zj = zbuf[j];
        float dx = z0 - zj.x;
        float dy = z1 - zj.y;
        float dz = z2 - zj.z;
        float sq = dx * dx + dy * dy + dz * dz;
        Lsh[lane * 65 + j] = sf2 * EXP2F(-0.5f * LOG2E * sq);
    }
    __syncthreads();

    Rows r;
    load_row(r, &Lsh[lane * 65], std::make_integer_sequence<int, 64>{});

    chol_phase< 0, 32,  0>(r, Lsh, lkbuf, lane);
    chol_phase<32, 48, 32>(r, Lsh, lkbuf, lane);
    chol_phase<48, 64, 48>(r, Lsh, lkbuf, lane);
    __syncthreads();

    // Solve L^T W = U (column sweep, descending i).
    float s0 = U[lane * 2 + 0];
    float s1 = U[lane * 2 + 1];
    float w0v = 0.0f, w1v = 0.0f;
#pragma unroll 8
    for (int i = 63; i >= 0; --i) {
        float a   = Lsh[i * 65 + lane];    // L[i][lane]; lane i: 1/L[i][i]
        float rdi = RDLANE(a, i);          // 1/L[i][i]
        float w0  = RDLANE(s0, i) * rdi;   // W[i][0]
        float w1  = RDLANE(s1, i) * rdi;   // W[i][1]
        bool  me  = (lane == i);
        w0v = me ? w0 : w0v;
        w1v = me ? w1 : w1v;
        s0 = fmaf(-a, w0, s0);             // lanes >= i polluted after use
        s1 = fmaf(-a, w1, s1);
    }

    const float dm = -0.5f * LOG2E * (z0 * z0 + z1 * z1 + z2 * z2);
    float4* ws4 = (float4*)ws;
    ws4[lane * 2 + 0] = make_float4(z0, z1, z2, dm);
    ws4[lane * 2 + 1] = make_float4(sf2 * w0v, sf2 * w1v, 0.0f, 0.0f);
}

// ---------------------------------------------------------------------------
// Kernel 2 (R14 body, grid-strided ~2 chunks/block -- best measured).
// ---------------------------------------------------------------------------
__global__ __launch_bounds__(256) void gp_forward(const float* __restrict__ X,
                                                  const float* __restrict__ ws,
                                                  const float* __restrict__ ell_p,
                                                  float* __restrict__ out,
                                                  int n, int nChunks) {
    __shared__ float4 P[128];   // 64 structs of {zs0,zs1,zs2,dm | w0,w1,0,0}
    for (int i = threadIdx.x; i < 128; i += 256)
        P[i] = ((const float4*)ws)[i];
    const float inv_ell = 1.0f / ell_p[0];
    __syncthreads();

    for (int chunk = blockIdx.x; chunk < nChunks; chunk += gridDim.x) {
        const int t  = chunk * 256 + (int)threadIdx.x;
        const int i0 = 2 * t;

        float p00, p01, p02, p10, p11, p12;
        if (i0 + 1 < n) {
            const float2* X2 = (const float2*)X;
            float2 xa = X2[3 * t + 0];
            float2 xb = X2[3 * t + 1];
            float2 xc = X2[3 * t + 2];
            p00 = xa.x; p01 = xa.y; p02 = xb.x;
            p10 = xb.y; p11 = xc.x; p12 = xc.y;
        } else if (i0 < n) {
            p00 = X[3 * i0 + 0]; p01 = X[3 * i0 + 1]; p02 = X[3 * i0 + 2];
            p10 = p00; p11 = p01; p12 = p02;
        } else {
            p00 = p01 = p02 = p10 = p11 = p12 = 0.0f;
        }

        float xt0[2], xt1[2], xt2[2], c[2];
        {
            float xs0 = p00 * inv_ell, xs1 = p01 * inv_ell, xs2 = p02 * inv_ell;
            c[0]  = -0.5f * LOG2E * (xs0 * xs0 + xs1 * xs1 + xs2 * xs2);
            xt0[0] = xs0 * LOG2E; xt1[0] = xs1 * LOG2E; xt2[0] = xs2 * LOG2E;
            xs0 = p10 * inv_ell; xs1 = p11 * inv_ell; xs2 = p12 * inv_ell;
            c[1]  = -0.5f * LOG2E * (xs0 * xs0 + xs1 * xs1 + xs2 * xs2);
            xt0[1] = xs0 * LOG2E; xt1[1] = xs1 * LOG2E; xt2[1] = xs2 * LOG2E;
        }

        float acc0[2] = {0.f, 0.f};
        float acc1[2] = {0.f, 0.f};

#pragma unroll 4
        for (int m = 0; m < 64; ++m) {
            const float4 a = P[2 * m + 0];
            const float4 b = P[2 * m + 1];
#pragma unroll
            for (int p = 0; p < 2; ++p) {
                float arg = fmaf(xt0[p], a.x,
                            fmaf(xt1[p], a.y,
                            fmaf(xt2[p], a.z, c[p] + a.w)));
                float e = EXP2F(arg);
                acc0[p] = fmaf(e, b.x, acc0[p]);
                acc1[p] = fmaf(e, b.y, acc1[p]);
            }
        }

        if (i0 + 1 < n) {
            ((float4*)out)[t] = make_float4(acc0[0], acc1[0], acc0[1], acc1[1]);
        } else if (i0 < n) {
            ((float2*)out)[i0] = make_float2(acc0[0], acc1[0]);
        }
    }
}

extern "C" void kernel_launch(void* const* d_in, const int* in_sizes, int n_in,
                              void* d_out, int out_size, void* d_ws, size_t ws_size,
                              hipStream_t stream) {
    // setup_inputs order: t, X, Z, U, sf, ell
    const float* X    = (const float*)d_in[1];
    const float* Z    = (const float*)d_in[2];
    const float* U    = (const float*)d_in[3];
    const float* sf   = (const float*)d_in[4];
    const float* ell  = (const float*)d_in[5];
    float* out = (float*)d_out;
    float* ws  = (float*)d_ws;
    const int N = in_sizes[1] / 3;

    gp_precompute<<<1, 64, 0, stream>>>(Z, U, sf, ell, ws);

    const int nChunks = (N + 511) / 512;    // 512 points (2/thread) per chunk
    int blocks = (nChunks + 1) / 2;         // ~2 chunks per block: 489 blocks
    if (blocks < 1) blocks = 1;
    gp_forward<<<blocks, 256, 0, stream>>>(X, ws, ell, out, N, nChunks);
}